// Round 6
// baseline (454.138 us; speedup 1.0000x reference)
//
#include <hip/hip_runtime.h>
#include <hip/hip_bf16.h>

#define NROW 384
#define GD   1935
#define GK   1952     // padded gate dim (61*32)
#define DD   300
#define KP   320      // padded o
#define DP   304      // padded p

// workspace offsets (in floats)
#define OFF_XBF  4112      // ushort XP[2][24][61][64][8]  frag-packed gated X
#define OFF_EBT  753680    // ushort EP[20][61][64][8]     frag-packed E^T
#define OFF_FC1B 1066000   // ushort[2][320][320]          fc1 plain
#define OFF_FC3B 1168400   // ushort[10][19][64][8]        fc3 frag-packed (kc-major)
#define OFF_F1B  1217040   // ushort[2][384][320]          gated-GEMM out (plain)
#define OFF_AB   1339920   // float: Ahat plain [384][320] | Bhat packed [24][10][64][8]
#define OFF_CD   1585680   // float: Chat plain [384][320] | Dhat packed [24][10][64][8]

typedef short short8 __attribute__((ext_vector_type(8)));
typedef float floatx4 __attribute__((ext_vector_type(4)));

__device__ inline unsigned short f2bf(float x){
  union { float f; unsigned u; } v; v.f = x;
  unsigned r = v.u + 0x7fffu + ((v.u >> 16) & 1u);
  return (unsigned short)(r >> 16);
}

// ---------------------------------------------------------------------------
// k_cvt_all — restructured.
// Blocks 0..383: X gate+convert via LDS TRANSPOSE (both sides coalesced).
//   old path read 16 rows/instr (16-line divergence, ~1.5M scattered loads).
//   block = (z, mt, chunk): 16 n-rows x 256 k; read coalesced (lane=k),
//   gate by LDS-cached sigmoid, emit frag-packed as contiguous 1KB stores.
// Blocks 384+: E / fc1 / fc3 as before (4-segment patterns, tolerable).
// ---------------------------------------------------------------------------
#define TE  (20*61*64)       // 78080
#define TF1 (2*320*40)       // 25600
#define TF3 (190*64)         // 12160
#define TREST (TE+TF1+TF3)   // 115840
#define XBLK 384             // 2 z * 24 mt * 8 chunks
#define GRID_CVT (XBLK + (TREST + 255)/256)   // 384 + 453
__global__ __launch_bounds__(256) void k_cvt_all(const float* f1, const float* f2,
                          const float* E, const float* g1, const float* g2,
                          const float* fc1w, const float* fc3w, float* ws){
  int bid = blockIdx.x, tid = threadIdx.x;
  if (bid < XBLK){
    __shared__ float sig[256];
    __shared__ __align__(16) unsigned short tile[16][264];  // +8 pad: 16B-aligned rows, <=2-way banks
    int z = bid / 192;
    int rem = bid - z*192;
    int mt = rem >> 3, chunk = rem & 7;
    const float* X = z ? f2 : f1;
    const float* g = z ? g2 : g1;
    int kbase = chunk * 256;
    {
      int k = kbase + tid;
      sig[tid] = (k < GD) ? 1.f/(1.f + expf(-g[k])) : 0.f;
    }
    __syncthreads();
    int k = kbase + tid;
    #pragma unroll
    for (int row = 0; row < 16; ++row){
      int n = mt*16 + row;
      float v = (k < GD) ? X[n*GD + k] * sig[tid] : 0.f;   // coalesced: lane = k
      tile[row][tid] = f2bf(v);
    }
    __syncthreads();
    unsigned short* xbf = (unsigned short*)(ws + OFF_XBF);
    int nkc = (chunk == 7) ? 5 : 8;                        // kc 56..60 only
    size_t obase = ((size_t)(z*24 + mt)*61 + chunk*8) * 512;
    for (int s = tid; s < nkc*64; s += 256){
      int kcl = s >> 6, lane2 = s & 63;
      int col2 = lane2 & 15, quad2 = lane2 >> 4;
      uint4 vv = *(const uint4*)&tile[col2][kcl*32 + quad2*8];
      *(uint4*)&xbf[obase + (size_t)s*8] = vv;             // contiguous 1KB/wave
    }
  } else {
    int t = (bid - XBLK)*256 + tid;
    unsigned short* ebt = (unsigned short*)(ws + OFF_EBT);
    unsigned short* f1b = (unsigned short*)(ws + OFF_FC1B);
    unsigned short* f3b = (unsigned short*)(ws + OFF_FC3B);
    if (t < TE){
      int i = t;
      int lane = i & 63;
      int rem = i >> 6;
      int kc = rem % 61, ct = rem / 61;
      int c  = ct*16 + (lane & 15);
      int k0 = kc*32 + (lane >> 4)*8;
      union { unsigned short s[8]; uint4 v; } u;
      #pragma unroll
      for (int e = 0; e < 8; ++e){
        int k = k0 + e;
        float v = (k < GD && c < DD) ? E[k*DD + c] : 0.f;
        u.s[e] = f2bf(v);
      }
      *(uint4*)&ebt[(size_t)i * 8] = u.v;
    } else if (t < TE + TF1){
      int i = t - TE;
      int d8 = i % 40; int o = (i/40) % 320; int z = i / (40*320);
      int d0 = d8*8;
      union { unsigned short s[8]; uint4 v; } u;
      #pragma unroll
      for (int e = 0; e < 8; ++e){
        int d = d0 + e;
        float v = (o < DD && d < DD) ? fc1w[o*(2*DD) + z*DD + d] : 0.f;
        u.s[e] = f2bf(v);
      }
      *(uint4*)&f1b[(size_t)((z*KP + o)*KP + d0)] = u.v;
    } else if (t < TREST){
      int i = t - TE - TF1;
      int lane = i & 63; int g = i >> 6;   // g = kc*19 + pt
      int pt = g % 19, kc = g / 19;
      int p  = pt*16 + (lane & 15);
      int k0 = kc*32 + (lane >> 4)*8;
      union { unsigned short s[8]; uint4 v; } u;
      #pragma unroll
      for (int e = 0; e < 8; ++e){
        int k = k0 + e;
        float v = (p < DD && k < DD) ? fc3w[p*DD + k] : 0.f;
        u.s[e] = f2bf(v);
      }
      *(uint4*)&f3b[(size_t)i * 8] = u.v;
    }
  }
}

// ---------------------------------------------------------------------------
// gated GEMM: F[z][384][320] = X @ E ; frag-packed inputs
// ---------------------------------------------------------------------------
__global__ __launch_bounds__(256) void k_gg(float* ws){
  int z = blockIdx.y;
  const unsigned short* XP = (const unsigned short*)(ws + OFF_XBF) + (size_t)z*24*61*512;
  const unsigned short* EP = (const unsigned short*)(ws + OFF_EBT);
  unsigned short* out      = (unsigned short*)(ws + OFF_F1B) + z*384*KP;
  int t = threadIdx.x, lane = t & 63;
  int id = blockIdx.x * 4 + (t >> 6);      // 0..479
  int mt = id / 20, ct = id - mt*20;
  int col = lane & 15, quad = lane >> 4;
  const unsigned short* ap = XP + (size_t)mt*61*512 + lane*8;
  const unsigned short* bp = EP + (size_t)ct*61*512 + lane*8;
  floatx4 acc = (floatx4){0.f,0.f,0.f,0.f};
  for (int kc = 0; kc < 61; ++kc){
    short8 a = *(const short8*)(ap + kc*512);
    short8 b = *(const short8*)(bp + kc*512);
    acc = __builtin_amdgcn_mfma_f32_16x16x32_bf16(a, b, acc, 0, 0, 0);
  }
  int c = ct*16 + col;
  #pragma unroll
  for (int r = 0; r < 4; ++r){
    int m = mt*16 + quad*4 + r;
    out[m*KP + c] = (c < DD) ? f2bf(acc[r]) : (unsigned short)0;
  }
}

// ---------------------------------------------------------------------------
// fused semantic + spatial. softmax(wloc) inlined per-thread.
// z=0 slabs (n-indexed) plain; z=1 slabs (m-indexed) frag-packed.
// ---------------------------------------------------------------------------
__global__ __launch_bounds__(256) void k_sesp(const float* fc1b, const float* box1,
                      const float* box2, const float* fc2w, const float* fc2b,
                      const float* wloc, float* ws){
  int z = blockIdx.y;
  float wa = wloc[0], wbv = wloc[1];
  float mm = fmaxf(wa, wbv);
  float ea = expf(wa - mm), eb = expf(wbv - mm);
  float w0 = ea / (ea + eb), w1 = eb / (ea + eb);
  int t = threadIdx.x;
  if (blockIdx.x < 120){
    const unsigned short* F = (const unsigned short*)(ws + OFF_F1B) + z*384*KP;
    const unsigned short* W = (const unsigned short*)(ws + OFF_FC1B) + z*KP*KP;
    int lane = t & 63;
    int id = blockIdx.x * 4 + (t >> 6);    // 0..479
    int rt = id / 20, ot = id - rt*20;
    int col = lane & 15, quad = lane >> 4;
    const unsigned short* ap = F + (rt*16 + col)*KP + quad*8;
    const unsigned short* bp = W + (ot*16 + col)*KP + quad*8;
    floatx4 acc = (floatx4){0.f,0.f,0.f,0.f};
    #pragma unroll
    for (int kc = 0; kc < 10; ++kc){
      short8 a = *(const short8*)(ap + kc*32);
      short8 b = *(const short8*)(bp + kc*32);
      acc = __builtin_amdgcn_mfma_f32_16x16x32_bf16(a, b, acc, 0, 0, 0);
    }
    int o = ot*16 + col;
    if (z == 0){
      float bias = (o < DD) ? fc1b[o] : 0.f;
      float* outp = ws + OFF_AB;
      #pragma unroll
      for (int r = 0; r < 4; ++r){
        int rr = rt*16 + quad*4 + r;
        outp[rr*KP + o] = (o < DD) ? w0 * (acc[r] + bias) : 0.f;
      }
    } else {
      float* BP = ws + OFF_AB + 384*KP;
      int kcs = o >> 5, q_o = (o >> 3) & 3, e = o & 7;
      #pragma unroll
      for (int r = 0; r < 4; ++r){
        int lm = quad*4 + r;
        BP[(rt*10 + kcs)*512 + (q_o*16 + lm)*8 + e] = (o < DD) ? w0 * acc[r] : 0.f;
      }
    }
  } else {
    int tt = (blockIdx.x - 120) * 256 + t;   // 0..122879
    int r = tt / KP, o = tt - r*KP;
    const float* bx = z ? box2 : box1;
    int joff = z ? 5 : 0;
    float v = 0.f;
    if (o < DD){
      const float* b = bx + r * 5;
      const float* wr = fc2w + o * 10 + joff;
      v = b[0]*wr[0] + b[1]*wr[1] + b[2]*wr[2] + b[3]*wr[3] + b[4]*wr[4];
      if (!z) v += fc2b[o];
      v *= w1;
    }
    if (z == 0) ws[OFF_CD + tt] = v;
    else {
      float* DPp = ws + OFF_CD + 384*KP;
      int mt = r >> 4, lm = r & 15, kcs = o >> 5, q_o = (o >> 3) & 3, e = o & 7;
      DPp[(mt*10 + kcs)*512 + (q_o*16 + lm)*8 + e] = v;
    }
  }
}

// ---------------------------------------------------------------------------
// main: out[n][m][p] = sum_o mixed(n,m,o)*fc3[p][o] + fc3b[p]
// Round-6: NORMAL stores (nt stores proved 1.7x write amplification: rows are
// 1200B so 64B chunks straddle lines; write-back L2 merges them — r5 PMC).
// Keep: counted barrier, 2-deep build pipeline, XCD grid partition (FETCH
// 24.6->3.9 MB proven). Occupancy: bounds (384,4) = 24 waves/CU target.
// ---------------------------------------------------------------------------
__global__ __launch_bounds__(384, 4) void k_main(const float* fc3b, float* out, const float* ws){
  __shared__ __align__(16) unsigned short wbuf[2][19*512];   // 2 x 19456 B
  const unsigned short* fc3p = (const unsigned short*)(ws + OFF_FC3B);
  int t = threadIdx.x;
  int lane = t & 63, wave = t >> 6;          // wave 0..5
  int col = lane & 15, quad = lane >> 4;
  int n = blockIdx.y;
  int mt = blockIdx.x * 6 + wave;            // 0..23
  const float* Ah = ws + OFF_AB + n * KP;
  const float* Ch = ws + OFF_CD + n * KP;
  const float* BP  = ws + OFF_AB + 384*KP + (size_t)mt*10*512 + lane*8;
  const float* DPp = ws + OFF_CD + 384*KP + (size_t)mt*10*512 + lane*8;

  floatx4 acc[19];
  #pragma unroll
  for (int i = 0; i < 19; ++i) acc[i] = (floatx4){0.f,0.f,0.f,0.f};

  // stage kc=0 weights (1216 uint4, 384 threads)
  {
    const uint4* src = (const uint4*)fc3p;
    uint4* dst = (uint4*)&wbuf[0][0];
    dst[t] = src[t]; dst[t + 384] = src[t + 384]; dst[t + 768] = src[t + 768];
    if (t < 64) dst[t + 1152] = src[t + 1152];
  }
  // preload kc=0 build operands
  float4 na0 = *(const float4*)(Ah + quad*8);
  float4 na1 = *(const float4*)(Ah + quad*8 + 4);
  float4 nc0 = *(const float4*)(Ch + quad*8);
  float4 nc1 = *(const float4*)(Ch + quad*8 + 4);
  float4 nb0 = *(const float4*)(BP);
  float4 nb1 = *(const float4*)(BP + 4);
  float4 nd0 = *(const float4*)(DPp);
  float4 nd1 = *(const float4*)(DPp + 4);
  __syncthreads();   // initial full drain (once)

  for (int kc = 0; kc < 10; ++kc){
    bool pre = (kc < 9);
    // weight prefetch for kc+1 — issued FIRST so the ds_write's vmcnt wait
    // leaves the (later-issued) build loads in flight
    uint4 s0, s1, s2, s3;
    if (pre){
      const uint4* src = (const uint4*)(fc3p + (size_t)(kc+1) * (19*512));
      s0 = src[t]; s1 = src[t + 384]; s2 = src[t + 768];
      if (t < 64) s3 = src[t + 1152];
    }
    // current build operands (loaded last iteration)
    float4 a0=na0, a1=na1, b0=nb0, b1=nb1, c0=nc0, c1=nc1, d0=nd0, d1=nd1;
    // issue next-kc build loads (stay in flight across the barrier)
    if (pre){
      int kb = (kc+1)*32 + quad*8;
      na0 = *(const float4*)(Ah + kb);   na1 = *(const float4*)(Ah + kb + 4);
      nc0 = *(const float4*)(Ch + kb);   nc1 = *(const float4*)(Ch + kb + 4);
      nb0 = *(const float4*)(BP + (kc+1)*512);  nb1 = *(const float4*)(BP + (kc+1)*512 + 4);
      nd0 = *(const float4*)(DPp + (kc+1)*512); nd1 = *(const float4*)(DPp + (kc+1)*512 + 4);
    }
    // build A-frag in registers
    union { unsigned short s[8]; short8 v8; } u;
    u.s[0] = f2bf(fmaxf(a0.x + b0.x, 0.f) + fmaxf(c0.x + d0.x, 0.f));
    u.s[1] = f2bf(fmaxf(a0.y + b0.y, 0.f) + fmaxf(c0.y + d0.y, 0.f));
    u.s[2] = f2bf(fmaxf(a0.z + b0.z, 0.f) + fmaxf(c0.z + d0.z, 0.f));
    u.s[3] = f2bf(fmaxf(a0.w + b0.w, 0.f) + fmaxf(c0.w + d0.w, 0.f));
    u.s[4] = f2bf(fmaxf(a1.x + b1.x, 0.f) + fmaxf(c1.x + d1.x, 0.f));
    u.s[5] = f2bf(fmaxf(a1.y + b1.y, 0.f) + fmaxf(c1.y + d1.y, 0.f));
    u.s[6] = f2bf(fmaxf(a1.z + b1.z, 0.f) + fmaxf(c1.z + d1.z, 0.f));
    u.s[7] = f2bf(fmaxf(a1.w + b1.w, 0.f) + fmaxf(c1.w + d1.w, 0.f));
    short8 af = u.v8;
    const unsigned short* wb = wbuf[kc & 1];
    #pragma unroll
    for (int pt = 0; pt < 19; ++pt){
      short8 bf = *(const short8*)(wb + pt*512 + lane*8);
      acc[pt] = __builtin_amdgcn_mfma_f32_16x16x32_bf16(af, bf, acc[pt], 0, 0, 0);
    }
    // write next weight slice, then barrier WITHOUT vmcnt drain
    if (pre){
      uint4* dst = (uint4*)&wbuf[(kc + 1) & 1][0];
      dst[t] = s0; dst[t + 384] = s1; dst[t + 768] = s2;
      if (t < 64) dst[t + 1152] = s3;
      asm volatile("s_waitcnt lgkmcnt(0)" ::: "memory");
      __builtin_amdgcn_s_barrier();
      __builtin_amdgcn_sched_barrier(0);   // rule #18: pin phase boundary
    }
  }

  #pragma unroll
  for (int pt = 0; pt < 19; ++pt){
    int p = pt*16 + col;
    if (p < DD){
      float bias = fc3b[p];
      #pragma unroll
      for (int r = 0; r < 4; ++r){
        int m = mt*16 + quad*4 + r;
        out[((size_t)n * NROW + m) * DD + p] = acc[pt][r] + bias;
      }
    }
  }
}

extern "C" void kernel_launch(void* const* d_in, const int* in_sizes, int n_in,
                              void* d_out, int out_size, void* d_ws, size_t ws_size,
                              hipStream_t stream) {
  const float* feature1 = (const float*)d_in[0];
  const float* box1     = (const float*)d_in[1];
  const float* feature2 = (const float*)d_in[2];
  const float* box2     = (const float*)d_in[3];
  const float* E        = (const float*)d_in[4];
  const float* gate1    = (const float*)d_in[5];
  const float* gate2    = (const float*)d_in[6];
  const float* wloc     = (const float*)d_in[7];
  const float* fc1w     = (const float*)d_in[8];
  const float* fc1b     = (const float*)d_in[9];
  const float* fc2w     = (const float*)d_in[10];
  const float* fc2b     = (const float*)d_in[11];
  const float* fc3w     = (const float*)d_in[12];
  const float* fc3b     = (const float*)d_in[13];
  float* out = (float*)d_out;
  float* ws  = (float*)d_ws;

  hipLaunchKernelGGL(k_cvt_all, dim3(GRID_CVT), dim3(256), 0, stream,
                     feature1, feature2, E, gate1, gate2, fc1w, fc3w, ws);
  hipLaunchKernelGGL(k_gg, dim3(120, 2), dim3(256), 0, stream, ws);
  hipLaunchKernelGGL(k_sesp, dim3(600, 2), dim3(256), 0, stream,
                     fc1b, box1, box2, fc2w, fc2b, wloc, ws);
  hipLaunchKernelGGL(k_main, dim3(4, NROW), dim3(384), 0, stream, fc3b, out, ws);
}

// Round 7
// 302.166 us; speedup vs baseline: 1.5029x; 1.5029x over previous
//
#include <hip/hip_runtime.h>
#include <hip/hip_bf16.h>

#define NROW 384
#define GD   1935
#define GK   1952     // padded gate dim (61*32)
#define DD   300
#define KP   320      // padded o
#define DP   304      // padded p

// workspace offsets (in floats)
#define OFF_XBF  4112      // ushort XP[2][24][61][64][8]  frag-packed gated X
#define OFF_EBT  753680    // ushort EP[20][61][64][8]     frag-packed E^T
#define OFF_FC1B 1066000   // ushort[2][320][320]          fc1 plain
#define OFF_FC3B 1168400   // ushort[10][19][64][8]        fc3 frag-packed (kc-major)
#define OFF_F1B  1217040   // ushort[2][384][320]          gated-GEMM out (plain)
#define OFF_AB   1339920   // float: Ahat plain [384][320] | Bhat packed [24][10][64][8]
#define OFF_CD   1585680   // float: Chat plain [384][320] | Dhat packed [24][10][64][8]

typedef short short8 __attribute__((ext_vector_type(8)));
typedef float floatx4 __attribute__((ext_vector_type(4)));

__device__ inline unsigned short f2bf(float x){
  union { float f; unsigned u; } v; v.f = x;
  unsigned r = v.u + 0x7fffu + ((v.u >> 16) & 1u);
  return (unsigned short)(r >> 16);
}

// ---------------------------------------------------------------------------
// k_cvt_all — unchanged from round 6 (X via LDS transpose, both sides coalesced)
// ---------------------------------------------------------------------------
#define TE  (20*61*64)       // 78080
#define TF1 (2*320*40)       // 25600
#define TF3 (190*64)         // 12160
#define TREST (TE+TF1+TF3)   // 115840
#define XBLK 384             // 2 z * 24 mt * 8 chunks
#define GRID_CVT (XBLK + (TREST + 255)/256)
__global__ __launch_bounds__(256) void k_cvt_all(const float* f1, const float* f2,
                          const float* E, const float* g1, const float* g2,
                          const float* fc1w, const float* fc3w, float* ws){
  int bid = blockIdx.x, tid = threadIdx.x;
  if (bid < XBLK){
    __shared__ float sig[256];
    __shared__ __align__(16) unsigned short tile[16][264];
    int z = bid / 192;
    int rem = bid - z*192;
    int mt = rem >> 3, chunk = rem & 7;
    const float* X = z ? f2 : f1;
    const float* g = z ? g2 : g1;
    int kbase = chunk * 256;
    {
      int k = kbase + tid;
      sig[tid] = (k < GD) ? 1.f/(1.f + expf(-g[k])) : 0.f;
    }
    __syncthreads();
    int k = kbase + tid;
    #pragma unroll
    for (int row = 0; row < 16; ++row){
      int n = mt*16 + row;
      float v = (k < GD) ? X[n*GD + k] * sig[tid] : 0.f;   // coalesced: lane = k
      tile[row][tid] = f2bf(v);
    }
    __syncthreads();
    unsigned short* xbf = (unsigned short*)(ws + OFF_XBF);
    int nkc = (chunk == 7) ? 5 : 8;
    size_t obase = ((size_t)(z*24 + mt)*61 + chunk*8) * 512;
    for (int s = tid; s < nkc*64; s += 256){
      int kcl = s >> 6, lane2 = s & 63;
      int col2 = lane2 & 15, quad2 = lane2 >> 4;
      uint4 vv = *(const uint4*)&tile[col2][kcl*32 + quad2*8];
      *(uint4*)&xbf[obase + (size_t)s*8] = vv;
    }
  } else {
    int t = (bid - XBLK)*256 + tid;
    unsigned short* ebt = (unsigned short*)(ws + OFF_EBT);
    unsigned short* f1b = (unsigned short*)(ws + OFF_FC1B);
    unsigned short* f3b = (unsigned short*)(ws + OFF_FC3B);
    if (t < TE){
      int i = t;
      int lane = i & 63;
      int rem = i >> 6;
      int kc = rem % 61, ct = rem / 61;
      int c  = ct*16 + (lane & 15);
      int k0 = kc*32 + (lane >> 4)*8;
      union { unsigned short s[8]; uint4 v; } u;
      #pragma unroll
      for (int e = 0; e < 8; ++e){
        int k = k0 + e;
        float v = (k < GD && c < DD) ? E[k*DD + c] : 0.f;
        u.s[e] = f2bf(v);
      }
      *(uint4*)&ebt[(size_t)i * 8] = u.v;
    } else if (t < TE + TF1){
      int i = t - TE;
      int d8 = i % 40; int o = (i/40) % 320; int z = i / (40*320);
      int d0 = d8*8;
      union { unsigned short s[8]; uint4 v; } u;
      #pragma unroll
      for (int e = 0; e < 8; ++e){
        int d = d0 + e;
        float v = (o < DD && d < DD) ? fc1w[o*(2*DD) + z*DD + d] : 0.f;
        u.s[e] = f2bf(v);
      }
      *(uint4*)&f1b[(size_t)((z*KP + o)*KP + d0)] = u.v;
    } else if (t < TREST){
      int i = t - TE - TF1;
      int lane = i & 63; int g = i >> 6;   // g = kc*19 + pt
      int pt = g % 19, kc = g / 19;
      int p  = pt*16 + (lane & 15);
      int k0 = kc*32 + (lane >> 4)*8;
      union { unsigned short s[8]; uint4 v; } u;
      #pragma unroll
      for (int e = 0; e < 8; ++e){
        int k = k0 + e;
        float v = (p < DD && k < DD) ? fc3w[p*DD + k] : 0.f;
        u.s[e] = f2bf(v);
      }
      *(uint4*)&f3b[(size_t)i * 8] = u.v;
    }
  }
}

// ---------------------------------------------------------------------------
// gated GEMM v2: F[z][384][320] = X @ E, 4-way K-SPLIT.
// Round-6 grid was 240 blocks (half the GPU idle, 1 wave/SIMD, latency fully
// exposed over 61 serial kc). Now: block = one 16x16 tile, 4 waves each
// covering 16|16|16|13 kc, LDS tree-reduce, all 256 threads store.
// 960 blocks -> ~4 blocks/CU, 4x the wave parallelism, 1/4 the serial depth.
// ---------------------------------------------------------------------------
__global__ __launch_bounds__(256) void k_gg(float* ws){
  __shared__ __align__(16) float red[4][64][4];   // 4 KB
  int z = blockIdx.y;
  const unsigned short* XP = (const unsigned short*)(ws + OFF_XBF) + (size_t)z*24*61*512;
  const unsigned short* EP = (const unsigned short*)(ws + OFF_EBT);
  unsigned short* out      = (unsigned short*)(ws + OFF_F1B) + z*384*KP;
  int t = threadIdx.x, lane = t & 63, wave = t >> 6;
  int id = blockIdx.x;                     // 0..479 tile id
  int mt = id / 20, ct = id - mt*20;
  const unsigned short* ap = XP + (size_t)mt*61*512 + lane*8;
  const unsigned short* bp = EP + (size_t)ct*61*512 + lane*8;
  int kc0 = wave*16;
  int kcn = (wave == 3) ? 13 : 16;
  floatx4 acc = (floatx4){0.f,0.f,0.f,0.f};
  for (int i = 0; i < kcn; ++i){
    int kc = kc0 + i;
    short8 a = *(const short8*)(ap + (size_t)kc*512);
    short8 b = *(const short8*)(bp + (size_t)kc*512);
    acc = __builtin_amdgcn_mfma_f32_16x16x32_bf16(a, b, acc, 0, 0, 0);
  }
  *(floatx4*)&red[wave][lane][0] = acc;
  __syncthreads();
  int r = t >> 6, lane2 = t & 63;
  float v = red[0][lane2][r] + red[1][lane2][r] + red[2][lane2][r] + red[3][lane2][r];
  int col = lane2 & 15, quad = lane2 >> 4;
  int m = mt*16 + quad*4 + r;
  int c = ct*16 + col;
  out[m*KP + c] = (c < DD) ? f2bf(v) : (unsigned short)0;
}

// ---------------------------------------------------------------------------
// fused semantic + spatial — unchanged from round 6.
// ---------------------------------------------------------------------------
__global__ __launch_bounds__(256) void k_sesp(const float* fc1b, const float* box1,
                      const float* box2, const float* fc2w, const float* fc2b,
                      const float* wloc, float* ws){
  int z = blockIdx.y;
  float wa = wloc[0], wbv = wloc[1];
  float mm = fmaxf(wa, wbv);
  float ea = expf(wa - mm), eb = expf(wbv - mm);
  float w0 = ea / (ea + eb), w1 = eb / (ea + eb);
  int t = threadIdx.x;
  if (blockIdx.x < 120){
    const unsigned short* F = (const unsigned short*)(ws + OFF_F1B) + z*384*KP;
    const unsigned short* W = (const unsigned short*)(ws + OFF_FC1B) + z*KP*KP;
    int lane = t & 63;
    int id = blockIdx.x * 4 + (t >> 6);    // 0..479
    int rt = id / 20, ot = id - rt*20;
    int col = lane & 15, quad = lane >> 4;
    const unsigned short* ap = F + (rt*16 + col)*KP + quad*8;
    const unsigned short* bp = W + (ot*16 + col)*KP + quad*8;
    floatx4 acc = (floatx4){0.f,0.f,0.f,0.f};
    #pragma unroll
    for (int kc = 0; kc < 10; ++kc){
      short8 a = *(const short8*)(ap + kc*32);
      short8 b = *(const short8*)(bp + kc*32);
      acc = __builtin_amdgcn_mfma_f32_16x16x32_bf16(a, b, acc, 0, 0, 0);
    }
    int o = ot*16 + col;
    if (z == 0){
      float bias = (o < DD) ? fc1b[o] : 0.f;
      float* outp = ws + OFF_AB;
      #pragma unroll
      for (int r = 0; r < 4; ++r){
        int rr = rt*16 + quad*4 + r;
        outp[rr*KP + o] = (o < DD) ? w0 * (acc[r] + bias) : 0.f;
      }
    } else {
      float* BP = ws + OFF_AB + 384*KP;
      int kcs = o >> 5, q_o = (o >> 3) & 3, e = o & 7;
      #pragma unroll
      for (int r = 0; r < 4; ++r){
        int lm = quad*4 + r;
        BP[(rt*10 + kcs)*512 + (q_o*16 + lm)*8 + e] = (o < DD) ? w0 * acc[r] : 0.f;
      }
    }
  } else {
    int tt = (blockIdx.x - 120) * 256 + t;   // 0..122879
    int r = tt / KP, o = tt - r*KP;
    const float* bx = z ? box2 : box1;
    int joff = z ? 5 : 0;
    float v = 0.f;
    if (o < DD){
      const float* b = bx + r * 5;
      const float* wr = fc2w + o * 10 + joff;
      v = b[0]*wr[0] + b[1]*wr[1] + b[2]*wr[2] + b[3]*wr[3] + b[4]*wr[4];
      if (!z) v += fc2b[o];
      v *= w1;
    }
    if (z == 0) ws[OFF_CD + tt] = v;
    else {
      float* DPp = ws + OFF_CD + 384*KP;
      int mt = r >> 4, lm = r & 15, kcs = o >> 5, q_o = (o >> 3) & 3, e = o & 7;
      DPp[(mt*10 + kcs)*512 + (q_o*16 + lm)*8 + e] = v;
    }
  }
}

// ---------------------------------------------------------------------------
// main v7: pt-SPLIT for occupancy.
// The ~134 µs wall across r0/r2/r3 was register-occupancy: acc[19] (76 AGPR)
// + ~68 arch = ~144/512-per-SIMD pool -> 3 waves/SIMD (= measured 37%).
// Now: 8 waves = 4 mt x 2 pt-groups, acc[10] (40 AGPR), ~112 total ->
// 4 waves/SIMD. Bounds (512,3): no forced spill (r6 lesson: a too-tight
// min-occupancy bound spills the prefetch pipeline into 460 MB of scratch).
// Normal stores (r5: nt stores = 1.7x write amplification on 1200B rows).
// Keep: counted barrier, 2-deep prefetch, frag-packed operands.
// ---------------------------------------------------------------------------
__global__ __launch_bounds__(512, 3) void k_main(const float* fc3b, float* out, const float* ws){
  __shared__ __align__(16) unsigned short wbuf[2][19*512];   // 2 x 19456 B
  const unsigned short* fc3p = (const unsigned short*)(ws + OFF_FC3B);
  int t = threadIdx.x;
  int lane = t & 63, wave = t >> 6;          // 0..7
  int col = lane & 15, quad = lane >> 4;
  int mtw = wave >> 1, pg = wave & 1;        // mt-sub, pt-group
  int n = blockIdx.y;
  int mt = blockIdx.x * 4 + mtw;             // 0..23
  const float* Ah = ws + OFF_AB + n * KP;
  const float* Ch = ws + OFF_CD + n * KP;
  const float* BP  = ws + OFF_AB + 384*KP + (size_t)mt*10*512 + lane*8;
  const float* DPp = ws + OFF_CD + 384*KP + (size_t)mt*10*512 + lane*8;

  floatx4 acc[10];
  #pragma unroll
  for (int i = 0; i < 10; ++i) acc[i] = (floatx4){0.f,0.f,0.f,0.f};

  // stage kc=0 weights (1216 uint4, 512 threads)
  {
    const uint4* src = (const uint4*)fc3p;
    uint4* dst = (uint4*)&wbuf[0][0];
    dst[t] = src[t]; dst[t + 512] = src[t + 512];
    if (t < 192) dst[t + 1024] = src[t + 1024];
  }
  // preload kc=0 build operands
  float4 na0 = *(const float4*)(Ah + quad*8);
  float4 na1 = *(const float4*)(Ah + quad*8 + 4);
  float4 nc0 = *(const float4*)(Ch + quad*8);
  float4 nc1 = *(const float4*)(Ch + quad*8 + 4);
  float4 nb0 = *(const float4*)(BP);
  float4 nb1 = *(const float4*)(BP + 4);
  float4 nd0 = *(const float4*)(DPp);
  float4 nd1 = *(const float4*)(DPp + 4);
  __syncthreads();   // initial full drain (once)

  for (int kc = 0; kc < 10; ++kc){
    bool pre = (kc < 9);
    // weight prefetch for kc+1 (issued first; its regs retire at ds_write)
    uint4 s0, s1, s2;
    if (pre){
      const uint4* src = (const uint4*)(fc3p + (size_t)(kc+1) * (19*512));
      s0 = src[t]; s1 = src[t + 512];
      if (t < 192) s2 = src[t + 1024];
    }
    float4 a0=na0, a1=na1, b0=nb0, b1=nb1, c0=nc0, c1=nc1, d0=nd0, d1=nd1;
    // issue next-kc build loads (stay in flight across the barrier)
    if (pre){
      int kb = (kc+1)*32 + quad*8;
      na0 = *(const float4*)(Ah + kb);   na1 = *(const float4*)(Ah + kb + 4);
      nc0 = *(const float4*)(Ch + kb);   nc1 = *(const float4*)(Ch + kb + 4);
      nb0 = *(const float4*)(BP + (kc+1)*512);  nb1 = *(const float4*)(BP + (kc+1)*512 + 4);
      nd0 = *(const float4*)(DPp + (kc+1)*512); nd1 = *(const float4*)(DPp + (kc+1)*512 + 4);
    }
    // build A-frag in registers (both pg waves of an mt build the same frag)
    union { unsigned short s[8]; short8 v8; } u;
    u.s[0] = f2bf(fmaxf(a0.x + b0.x, 0.f) + fmaxf(c0.x + d0.x, 0.f));
    u.s[1] = f2bf(fmaxf(a0.y + b0.y, 0.f) + fmaxf(c0.y + d0.y, 0.f));
    u.s[2] = f2bf(fmaxf(a0.z + b0.z, 0.f) + fmaxf(c0.z + d0.z, 0.f));
    u.s[3] = f2bf(fmaxf(a0.w + b0.w, 0.f) + fmaxf(c0.w + d0.w, 0.f));
    u.s[4] = f2bf(fmaxf(a1.x + b1.x, 0.f) + fmaxf(c1.x + d1.x, 0.f));
    u.s[5] = f2bf(fmaxf(a1.y + b1.y, 0.f) + fmaxf(c1.y + d1.y, 0.f));
    u.s[6] = f2bf(fmaxf(a1.z + b1.z, 0.f) + fmaxf(c1.z + d1.z, 0.f));
    u.s[7] = f2bf(fmaxf(a1.w + b1.w, 0.f) + fmaxf(c1.w + d1.w, 0.f));
    short8 af = u.v8;
    const unsigned short* wb = wbuf[kc & 1];
    #pragma unroll
    for (int i = 0; i < 10; ++i){
      int pt = pg*10 + i;
      if (pt < 19){
        short8 bf = *(const short8*)(wb + pt*512 + lane*8);
        acc[i] = __builtin_amdgcn_mfma_f32_16x16x32_bf16(af, bf, acc[i], 0, 0, 0);
      }
    }
    // write next weight slice, then barrier WITHOUT vmcnt drain
    if (pre){
      uint4* dst = (uint4*)&wbuf[(kc + 1) & 1][0];
      dst[t] = s0; dst[t + 512] = s1;
      if (t < 192) dst[t + 1024] = s2;
      asm volatile("s_waitcnt lgkmcnt(0)" ::: "memory");
      __builtin_amdgcn_s_barrier();
      __builtin_amdgcn_sched_barrier(0);   // rule #18: pin phase boundary
    }
  }

  #pragma unroll
  for (int i = 0; i < 10; ++i){
    int pt = pg*10 + i;
    int p = pt*16 + col;
    if (pt < 19 && p < DD){
      float bias = fc3b[p];
      #pragma unroll
      for (int r = 0; r < 4; ++r){
        int m = mt*16 + quad*4 + r;
        out[((size_t)n * NROW + m) * DD + p] = acc[i][r] + bias;
      }
    }
  }
}

extern "C" void kernel_launch(void* const* d_in, const int* in_sizes, int n_in,
                              void* d_out, int out_size, void* d_ws, size_t ws_size,
                              hipStream_t stream) {
  const float* feature1 = (const float*)d_in[0];
  const float* box1     = (const float*)d_in[1];
  const float* feature2 = (const float*)d_in[2];
  const float* box2     = (const float*)d_in[3];
  const float* E        = (const float*)d_in[4];
  const float* gate1    = (const float*)d_in[5];
  const float* gate2    = (const float*)d_in[6];
  const float* wloc     = (const float*)d_in[7];
  const float* fc1w     = (const float*)d_in[8];
  const float* fc1b     = (const float*)d_in[9];
  const float* fc2w     = (const float*)d_in[10];
  const float* fc2b     = (const float*)d_in[11];
  const float* fc3w     = (const float*)d_in[12];
  const float* fc3b     = (const float*)d_in[13];
  float* out = (float*)d_out;
  float* ws  = (float*)d_ws;

  hipLaunchKernelGGL(k_cvt_all, dim3(GRID_CVT), dim3(256), 0, stream,
                     feature1, feature2, E, gate1, gate2, fc1w, fc3w, ws);
  hipLaunchKernelGGL(k_gg, dim3(480, 2), dim3(256), 0, stream, ws);
  hipLaunchKernelGGL(k_sesp, dim3(600, 2), dim3(256), 0, stream,
                     fc1b, box1, box2, fc2w, fc2b, wloc, ws);
  hipLaunchKernelGGL(k_main, dim3(6, NROW), dim3(512), 0, stream, fc3b, out, ws);
}

// Round 9
// 286.922 us; speedup vs baseline: 1.5828x; 1.0531x over previous
//
#include <hip/hip_runtime.h>
#include <hip/hip_bf16.h>

#define NROW 384
#define GD   1935
#define GK   1952     // padded gate dim (61*32)
#define DD   300
#define KP   320      // padded o
#define DP   304      // padded p

// workspace offsets (in floats)
#define OFF_XBF  4112      // ushort XP[2][24][61][64][8]  frag-packed gated X
#define OFF_EBT  753680    // ushort EP[20][61][64][8]     frag-packed E^T
#define OFF_FC1B 1066000   // ushort[2][320][320]          fc1 plain
#define OFF_FC3B 1168400   // ushort[10][19][64][8]        fc3 frag-packed (kc-major)
#define OFF_F1B  1217040   // ushort[2][384][320]          gated-GEMM out (plain)
#define OFF_AB   1339920   // float: Ahat plain [384][320] | Bhat packed [24][10][64][8]
#define OFF_CD   1585680   // float: Chat plain [384][320] | Dhat packed [24][10][64][8]

typedef short short8 __attribute__((ext_vector_type(8)));
typedef float floatx4 __attribute__((ext_vector_type(4)));

__device__ inline unsigned short f2bf(float x){
  union { float f; unsigned u; } v; v.f = x;
  unsigned r = v.u + 0x7fffu + ((v.u >> 16) & 1u);
  return (unsigned short)(r >> 16);
}

// ---------------------------------------------------------------------------
// k_cvt_all — X via LDS transpose + E/fc1/fc3 conversions + SPATIAL (fused in:
// spatial has no dependency on k_gg, so it rides the first kernel free).
// ---------------------------------------------------------------------------
#define TE  (20*61*64)       // 78080
#define TF1 (2*320*40)       // 25600
#define TF3 (190*64)         // 12160
#define TREST (TE+TF1+TF3)   // 115840
#define XBLK 384             // 2 z * 24 mt * 8 chunks
#define RBLK ((TREST + 255)/256)   // 453
#define SBLK 960             // spatial: 2 z * 480
#define GRID_CVT (XBLK + RBLK + SBLK)
__global__ __launch_bounds__(256) void k_cvt_all(const float* f1, const float* f2,
                          const float* E, const float* g1, const float* g2,
                          const float* fc1w, const float* fc3w,
                          const float* box1, const float* box2,
                          const float* fc2w, const float* fc2b,
                          const float* wloc, float* ws){
  int bid = blockIdx.x, tid = threadIdx.x;
  if (bid < XBLK){
    __shared__ float sig[256];
    __shared__ __align__(16) unsigned short tile[16][264];
    int z = bid / 192;
    int rem = bid - z*192;
    int mt = rem >> 3, chunk = rem & 7;
    const float* X = z ? f2 : f1;
    const float* g = z ? g2 : g1;
    int kbase = chunk * 256;
    {
      int k = kbase + tid;
      sig[tid] = (k < GD) ? 1.f/(1.f + expf(-g[k])) : 0.f;
    }
    __syncthreads();
    int k = kbase + tid;
    #pragma unroll
    for (int row = 0; row < 16; ++row){
      int n = mt*16 + row;
      float v = (k < GD) ? X[n*GD + k] * sig[tid] : 0.f;   // coalesced: lane = k
      tile[row][tid] = f2bf(v);
    }
    __syncthreads();
    unsigned short* xbf = (unsigned short*)(ws + OFF_XBF);
    int nkc = (chunk == 7) ? 5 : 8;
    size_t obase = ((size_t)(z*24 + mt)*61 + chunk*8) * 512;
    for (int s = tid; s < nkc*64; s += 256){
      int kcl = s >> 6, lane2 = s & 63;
      int col2 = lane2 & 15, quad2 = lane2 >> 4;
      uint4 vv = *(const uint4*)&tile[col2][kcl*32 + quad2*8];
      *(uint4*)&xbf[obase + (size_t)s*8] = vv;
    }
  } else if (bid < XBLK + RBLK){
    int t = (bid - XBLK)*256 + tid;
    unsigned short* ebt = (unsigned short*)(ws + OFF_EBT);
    unsigned short* f1b = (unsigned short*)(ws + OFF_FC1B);
    unsigned short* f3b = (unsigned short*)(ws + OFF_FC3B);
    if (t < TE){
      int i = t;
      int lane = i & 63;
      int rem = i >> 6;
      int kc = rem % 61, ct = rem / 61;
      int c  = ct*16 + (lane & 15);
      int k0 = kc*32 + (lane >> 4)*8;
      union { unsigned short s[8]; uint4 v; } u;
      #pragma unroll
      for (int e = 0; e < 8; ++e){
        int k = k0 + e;
        float v = (k < GD && c < DD) ? E[k*DD + c] : 0.f;
        u.s[e] = f2bf(v);
      }
      *(uint4*)&ebt[(size_t)i * 8] = u.v;
    } else if (t < TE + TF1){
      int i = t - TE;
      int d8 = i % 40; int o = (i/40) % 320; int z = i / (40*320);
      int d0 = d8*8;
      union { unsigned short s[8]; uint4 v; } u;
      #pragma unroll
      for (int e = 0; e < 8; ++e){
        int d = d0 + e;
        float v = (o < DD && d < DD) ? fc1w[o*(2*DD) + z*DD + d] : 0.f;
        u.s[e] = f2bf(v);
      }
      *(uint4*)&f1b[(size_t)((z*KP + o)*KP + d0)] = u.v;
    } else if (t < TREST){
      int i = t - TE - TF1;
      int lane = i & 63; int g = i >> 6;   // g = kc*19 + pt
      int pt = g % 19, kc = g / 19;
      int p  = pt*16 + (lane & 15);
      int k0 = kc*32 + (lane >> 4)*8;
      union { unsigned short s[8]; uint4 v; } u;
      #pragma unroll
      for (int e = 0; e < 8; ++e){
        int k = k0 + e;
        float v = (p < DD && k < DD) ? fc3w[p*DD + k] : 0.f;
        u.s[e] = f2bf(v);
      }
      *(uint4*)&f3b[(size_t)i * 8] = u.v;
    }
  } else {
    // ---- spatial: box @ fc2 half; z=0 plain, z=1 frag-packed ----
    int sid = bid - XBLK - RBLK;
    int z = sid / 480;
    int tt = (sid - z*480) * 256 + tid;      // 0..122879
    float wa = wloc[0], wbv = wloc[1];
    float mm = fmaxf(wa, wbv);
    float ea = expf(wa - mm), eb = expf(wbv - mm);
    float w1 = eb / (ea + eb);
    int r = tt / KP, o = tt - r*KP;
    const float* bx = z ? box2 : box1;
    int joff = z ? 5 : 0;
    float v = 0.f;
    if (o < DD){
      const float* b = bx + r * 5;
      const float* wr = fc2w + o * 10 + joff;
      v = b[0]*wr[0] + b[1]*wr[1] + b[2]*wr[2] + b[3]*wr[3] + b[4]*wr[4];
      if (!z) v += fc2b[o];
      v *= w1;
    }
    if (z == 0) ws[OFF_CD + tt] = v;
    else {
      float* DPp = ws + OFF_CD + 384*KP;
      int mt = r >> 4, lm = r & 15, kcs = o >> 5, q_o = (o >> 3) & 3, e = o & 7;
      DPp[(mt*10 + kcs)*512 + (q_o*16 + lm)*8 + e] = v;
    }
  }
}

// ---------------------------------------------------------------------------
// gated GEMM: 4-way K-split, unchanged (proven in round 7).
// ---------------------------------------------------------------------------
__global__ __launch_bounds__(256) void k_gg(float* ws){
  __shared__ __align__(16) float red[4][64][4];   // 4 KB
  int z = blockIdx.y;
  const unsigned short* XP = (const unsigned short*)(ws + OFF_XBF) + (size_t)z*24*61*512;
  const unsigned short* EP = (const unsigned short*)(ws + OFF_EBT);
  unsigned short* out      = (unsigned short*)(ws + OFF_F1B) + z*384*KP;
  int t = threadIdx.x, lane = t & 63, wave = t >> 6;
  int id = blockIdx.x;                     // 0..479 tile id
  int mt = id / 20, ct = id - mt*20;
  const unsigned short* ap = XP + (size_t)mt*61*512 + lane*8;
  const unsigned short* bp = EP + (size_t)ct*61*512 + lane*8;
  int kc0 = wave*16;
  int kcn = (wave == 3) ? 13 : 16;
  floatx4 acc = (floatx4){0.f,0.f,0.f,0.f};
  for (int i = 0; i < kcn; ++i){
    int kc = kc0 + i;
    short8 a = *(const short8*)(ap + (size_t)kc*512);
    short8 b = *(const short8*)(bp + (size_t)kc*512);
    acc = __builtin_amdgcn_mfma_f32_16x16x32_bf16(a, b, acc, 0, 0, 0);
  }
  *(floatx4*)&red[wave][lane][0] = acc;
  __syncthreads();
  int r = t >> 6, lane2 = t & 63;
  float v = red[0][lane2][r] + red[1][lane2][r] + red[2][lane2][r] + red[3][lane2][r];
  int col = lane2 & 15, quad = lane2 >> 4;
  int m = mt*16 + quad*4 + r;
  int c = ct*16 + col;
  out[m*KP + c] = (c < DD) ? f2bf(v) : (unsigned short)0;
}

// ---------------------------------------------------------------------------
// semantic only (spatial moved to k_cvt_all): AB = w0*(F @ fc1^T (+b1))
// ---------------------------------------------------------------------------
__global__ __launch_bounds__(256) void k_sem(const float* fc1b, const float* wloc, float* ws){
  int z = blockIdx.y;
  float wa = wloc[0], wbv = wloc[1];
  float mm = fmaxf(wa, wbv);
  float ea = expf(wa - mm), eb = expf(wbv - mm);
  float w0 = ea / (ea + eb);
  int t = threadIdx.x;
  const unsigned short* F = (const unsigned short*)(ws + OFF_F1B) + z*384*KP;
  const unsigned short* W = (const unsigned short*)(ws + OFF_FC1B) + z*KP*KP;
  int lane = t & 63;
  int id = blockIdx.x * 4 + (t >> 6);    // 0..479
  int rt = id / 20, ot = id - rt*20;
  int col = lane & 15, quad = lane >> 4;
  const unsigned short* ap = F + (rt*16 + col)*KP + quad*8;
  const unsigned short* bp = W + (ot*16 + col)*KP + quad*8;
  floatx4 acc = (floatx4){0.f,0.f,0.f,0.f};
  #pragma unroll
  for (int kc = 0; kc < 10; ++kc){
    short8 a = *(const short8*)(ap + kc*32);
    short8 b = *(const short8*)(bp + kc*32);
    acc = __builtin_amdgcn_mfma_f32_16x16x32_bf16(a, b, acc, 0, 0, 0);
  }
  int o = ot*16 + col;
  if (z == 0){
    float bias = (o < DD) ? fc1b[o] : 0.f;
    float* outp = ws + OFF_AB;
    #pragma unroll
    for (int r = 0; r < 4; ++r){
      int rr = rt*16 + quad*4 + r;
      outp[rr*KP + o] = (o < DD) ? w0 * (acc[r] + bias) : 0.f;
    }
  } else {
    float* BP = ws + OFF_AB + 384*KP;
    int kcs = o >> 5, q_o = (o >> 3) & 3, e = o & 7;
    #pragma unroll
    for (int r = 0; r < 4; ++r){
      int lm = quad*4 + r;
      BP[(rt*10 + kcs)*512 + (q_o*16 + lm)*8 + e] = (o < DD) ? w0 * acc[r] : 0.f;
    }
  }
}

// ---------------------------------------------------------------------------
// main v8b: 256-thread blocks for co-residency.
// r7 measured: 512-thr blocks -> Occupancy 21%, latency exposed at each of
// the 10 counted barriers. 256-thr blocks (4 waves = 2 mt x 2 pg) keep
// per-wave work identical but halve residency granularity: ~4 blocks/CU
// (LDS 4x38.9=155<=160 KB, regs ~116). Bounds (256,3): never force a
// spill (r6 lesson). Scalar f2bf converts (m240: inline-asm cvt_pk is
// slower — compiler handles scalar casts; also removes the only
// hardware-untested element after the r8 infra failure).
// ---------------------------------------------------------------------------
__global__ __launch_bounds__(256, 3) void k_main(const float* fc3b, float* out, const float* ws){
  __shared__ __align__(16) unsigned short wbuf[2][19*512];   // 2 x 19456 B
  const unsigned short* fc3p = (const unsigned short*)(ws + OFF_FC3B);
  int t = threadIdx.x;
  int lane = t & 63, wave = t >> 6;          // 0..3
  int col = lane & 15, quad = lane >> 4;
  int mtw = wave >> 1, pg = wave & 1;        // mt-sub, pt-group
  int n = blockIdx.y;
  int mt = blockIdx.x * 2 + mtw;             // 0..23
  const float* Ah = ws + OFF_AB + n * KP;
  const float* Ch = ws + OFF_CD + n * KP;
  const float* BP  = ws + OFF_AB + 384*KP + (size_t)mt*10*512 + lane*8;
  const float* DPp = ws + OFF_CD + 384*KP + (size_t)mt*10*512 + lane*8;

  floatx4 acc[10];
  #pragma unroll
  for (int i = 0; i < 10; ++i) acc[i] = (floatx4){0.f,0.f,0.f,0.f};

  // stage kc=0 weights (1216 uint4, 256 threads -> 5 chunks)
  {
    const uint4* src = (const uint4*)fc3p;
    uint4* dst = (uint4*)&wbuf[0][0];
    dst[t] = src[t]; dst[t + 256] = src[t + 256];
    dst[t + 512] = src[t + 512]; dst[t + 768] = src[t + 768];
    if (t < 192) dst[t + 1024] = src[t + 1024];
  }
  // preload kc=0 build operands
  float4 na0 = *(const float4*)(Ah + quad*8);
  float4 na1 = *(const float4*)(Ah + quad*8 + 4);
  float4 nc0 = *(const float4*)(Ch + quad*8);
  float4 nc1 = *(const float4*)(Ch + quad*8 + 4);
  float4 nb0 = *(const float4*)(BP);
  float4 nb1 = *(const float4*)(BP + 4);
  float4 nd0 = *(const float4*)(DPp);
  float4 nd1 = *(const float4*)(DPp + 4);
  __syncthreads();   // initial full drain (once)

  for (int kc = 0; kc < 10; ++kc){
    bool pre = (kc < 9);
    // weight prefetch for kc+1 (issued first; regs retire at ds_write)
    uint4 s0, s1, s2, s3, s4;
    if (pre){
      const uint4* src = (const uint4*)(fc3p + (size_t)(kc+1) * (19*512));
      s0 = src[t]; s1 = src[t + 256]; s2 = src[t + 512]; s3 = src[t + 768];
      if (t < 192) s4 = src[t + 1024];
    }
    float4 a0=na0, a1=na1, b0=nb0, b1=nb1, c0=nc0, c1=nc1, d0=nd0, d1=nd1;
    // issue next-kc build loads (stay in flight across the barrier)
    if (pre){
      int kb = (kc+1)*32 + quad*8;
      na0 = *(const float4*)(Ah + kb);   na1 = *(const float4*)(Ah + kb + 4);
      nc0 = *(const float4*)(Ch + kb);   nc1 = *(const float4*)(Ch + kb + 4);
      nb0 = *(const float4*)(BP + (kc+1)*512);  nb1 = *(const float4*)(BP + (kc+1)*512 + 4);
      nd0 = *(const float4*)(DPp + (kc+1)*512); nd1 = *(const float4*)(DPp + (kc+1)*512 + 4);
    }
    // build A-frag: mixed = relu(a+b)+relu(c+d)
    union { unsigned short s[8]; short8 v8; } u;
    u.s[0] = f2bf(fmaxf(a0.x + b0.x, 0.f) + fmaxf(c0.x + d0.x, 0.f));
    u.s[1] = f2bf(fmaxf(a0.y + b0.y, 0.f) + fmaxf(c0.y + d0.y, 0.f));
    u.s[2] = f2bf(fmaxf(a0.z + b0.z, 0.f) + fmaxf(c0.z + d0.z, 0.f));
    u.s[3] = f2bf(fmaxf(a0.w + b0.w, 0.f) + fmaxf(c0.w + d0.w, 0.f));
    u.s[4] = f2bf(fmaxf(a1.x + b1.x, 0.f) + fmaxf(c1.x + d1.x, 0.f));
    u.s[5] = f2bf(fmaxf(a1.y + b1.y, 0.f) + fmaxf(c1.y + d1.y, 0.f));
    u.s[6] = f2bf(fmaxf(a1.z + b1.z, 0.f) + fmaxf(c1.z + d1.z, 0.f));
    u.s[7] = f2bf(fmaxf(a1.w + b1.w, 0.f) + fmaxf(c1.w + d1.w, 0.f));
    short8 af = u.v8;
    const unsigned short* wb = wbuf[kc & 1];
    #pragma unroll
    for (int i = 0; i < 10; ++i){
      int pt = pg*10 + i;
      if (pt < 19){
        short8 bf = *(const short8*)(wb + pt*512 + lane*8);
        acc[i] = __builtin_amdgcn_mfma_f32_16x16x32_bf16(af, bf, acc[i], 0, 0, 0);
      }
    }
    // write next weight slice, then barrier WITHOUT vmcnt drain
    if (pre){
      uint4* dst = (uint4*)&wbuf[(kc + 1) & 1][0];
      dst[t] = s0; dst[t + 256] = s1; dst[t + 512] = s2; dst[t + 768] = s3;
      if (t < 192) dst[t + 1024] = s4;
      asm volatile("s_waitcnt lgkmcnt(0)" ::: "memory");
      __builtin_amdgcn_s_barrier();
      __builtin_amdgcn_sched_barrier(0);   // rule #18: pin phase boundary
    }
  }

  #pragma unroll
  for (int i = 0; i < 10; ++i){
    int pt = pg*10 + i;
    int p = pt*16 + col;
    if (pt < 19 && p < DD){
      float bias = fc3b[p];
      #pragma unroll
      for (int r = 0; r < 4; ++r){
        int m = mt*16 + quad*4 + r;
        out[((size_t)n * NROW + m) * DD + p] = acc[i][r] + bias;
      }
    }
  }
}

extern "C" void kernel_launch(void* const* d_in, const int* in_sizes, int n_in,
                              void* d_out, int out_size, void* d_ws, size_t ws_size,
                              hipStream_t stream) {
  const float* feature1 = (const float*)d_in[0];
  const float* box1     = (const float*)d_in[1];
  const float* feature2 = (const float*)d_in[2];
  const float* box2     = (const float*)d_in[3];
  const float* E        = (const float*)d_in[4];
  const float* gate1    = (const float*)d_in[5];
  const float* gate2    = (const float*)d_in[6];
  const float* wloc     = (const float*)d_in[7];
  const float* fc1w     = (const float*)d_in[8];
  const float* fc1b     = (const float*)d_in[9];
  const float* fc2w     = (const float*)d_in[10];
  const float* fc2b     = (const float*)d_in[11];
  const float* fc3w     = (const float*)d_in[12];
  const float* fc3b     = (const float*)d_in[13];
  float* out = (float*)d_out;
  float* ws  = (float*)d_ws;

  hipLaunchKernelGGL(k_cvt_all, dim3(GRID_CVT), dim3(256), 0, stream,
                     feature1, feature2, E, gate1, gate2, fc1w, fc3w,
                     box1, box2, fc2w, fc2b, wloc, ws);
  hipLaunchKernelGGL(k_gg, dim3(480, 2), dim3(256), 0, stream, ws);
  hipLaunchKernelGGL(k_sem, dim3(120, 2), dim3(256), 0, stream, fc1b, wloc, ws);
  hipLaunchKernelGGL(k_main, dim3(12, NROW), dim3(256), 0, stream, fc3b, out, ws);
}

// Round 10
// 279.992 us; speedup vs baseline: 1.6220x; 1.0248x over previous
//
#include <hip/hip_runtime.h>
#include <hip/hip_bf16.h>

#define NROW 384
#define GD   1935
#define GK   1952     // padded gate dim (61*32)
#define DD   300
#define KP   320      // padded o
#define DP   304      // padded p

// workspace offsets (in floats)
#define OFF_XBF  4112      // ushort XP[2][24][61][64][8]  frag-packed gated X
#define OFF_EBT  753680    // ushort EP[20][61][64][8]     frag-packed E^T
#define OFF_FC1B 1066000   // ushort[2][320][320]          fc1 plain
#define OFF_FC3B 1168400   // ushort[10][19][64][8]        fc3 frag-packed (kc-major)
#define OFF_F1B  1217040   // ushort[2][384][320]          gated-GEMM out (plain)
#define OFF_AB   1339920   // float: Ahat plain [384][320] | Bhat packed [24][10][64][8]
#define OFF_CD   1585680   // float: Chat plain [384][320] | Dhat packed [24][10][64][8]

typedef short short8 __attribute__((ext_vector_type(8)));
typedef float floatx4 __attribute__((ext_vector_type(4)));

__device__ inline unsigned short f2bf(float x){
  union { float f; unsigned u; } v; v.f = x;
  unsigned r = v.u + 0x7fffu + ((v.u >> 16) & 1u);
  return (unsigned short)(r >> 16);
}

// native RNE cast (same bits as f2bf); compiler can pair these into
// v_cvt_pk_bf16_f32 (m240: scalar casts are the fast path, not inline asm)
__device__ inline unsigned short c2bf(float x){
  __hip_bfloat16 b = __float2bfloat16(x);
  unsigned short s;
  __builtin_memcpy(&s, &b, 2);
  return s;
}

// ---------------------------------------------------------------------------
// k_cvt_all — X via LDS transpose + E/fc1/fc3 conversions + SPATIAL (fused).
// Unchanged from round 9 (passing, ~part of the 70 µs middle budget).
// ---------------------------------------------------------------------------
#define TE  (20*61*64)       // 78080
#define TF1 (2*320*40)       // 25600
#define TF3 (190*64)         // 12160
#define TREST (TE+TF1+TF3)   // 115840
#define XBLK 384             // 2 z * 24 mt * 8 chunks
#define RBLK ((TREST + 255)/256)   // 453
#define SBLK 960             // spatial: 2 z * 480
#define GRID_CVT (XBLK + RBLK + SBLK)
__global__ __launch_bounds__(256) void k_cvt_all(const float* f1, const float* f2,
                          const float* E, const float* g1, const float* g2,
                          const float* fc1w, const float* fc3w,
                          const float* box1, const float* box2,
                          const float* fc2w, const float* fc2b,
                          const float* wloc, float* ws){
  int bid = blockIdx.x, tid = threadIdx.x;
  if (bid < XBLK){
    __shared__ float sig[256];
    __shared__ __align__(16) unsigned short tile[16][264];
    int z = bid / 192;
    int rem = bid - z*192;
    int mt = rem >> 3, chunk = rem & 7;
    const float* X = z ? f2 : f1;
    const float* g = z ? g2 : g1;
    int kbase = chunk * 256;
    {
      int k = kbase + tid;
      sig[tid] = (k < GD) ? 1.f/(1.f + expf(-g[k])) : 0.f;
    }
    __syncthreads();
    int k = kbase + tid;
    #pragma unroll
    for (int row = 0; row < 16; ++row){
      int n = mt*16 + row;
      float v = (k < GD) ? X[n*GD + k] * sig[tid] : 0.f;   // coalesced: lane = k
      tile[row][tid] = f2bf(v);
    }
    __syncthreads();
    unsigned short* xbf = (unsigned short*)(ws + OFF_XBF);
    int nkc = (chunk == 7) ? 5 : 8;
    size_t obase = ((size_t)(z*24 + mt)*61 + chunk*8) * 512;
    for (int s = tid; s < nkc*64; s += 256){
      int kcl = s >> 6, lane2 = s & 63;
      int col2 = lane2 & 15, quad2 = lane2 >> 4;
      uint4 vv = *(const uint4*)&tile[col2][kcl*32 + quad2*8];
      *(uint4*)&xbf[obase + (size_t)s*8] = vv;
    }
  } else if (bid < XBLK + RBLK){
    int t = (bid - XBLK)*256 + tid;
    unsigned short* ebt = (unsigned short*)(ws + OFF_EBT);
    unsigned short* f1b = (unsigned short*)(ws + OFF_FC1B);
    unsigned short* f3b = (unsigned short*)(ws + OFF_FC3B);
    if (t < TE){
      int i = t;
      int lane = i & 63;
      int rem = i >> 6;
      int kc = rem % 61, ct = rem / 61;
      int c  = ct*16 + (lane & 15);
      int k0 = kc*32 + (lane >> 4)*8;
      union { unsigned short s[8]; uint4 v; } u;
      #pragma unroll
      for (int e = 0; e < 8; ++e){
        int k = k0 + e;
        float v = (k < GD && c < DD) ? E[k*DD + c] : 0.f;
        u.s[e] = f2bf(v);
      }
      *(uint4*)&ebt[(size_t)i * 8] = u.v;
    } else if (t < TE + TF1){
      int i = t - TE;
      int d8 = i % 40; int o = (i/40) % 320; int z = i / (40*320);
      int d0 = d8*8;
      union { unsigned short s[8]; uint4 v; } u;
      #pragma unroll
      for (int e = 0; e < 8; ++e){
        int d = d0 + e;
        float v = (o < DD && d < DD) ? fc1w[o*(2*DD) + z*DD + d] : 0.f;
        u.s[e] = f2bf(v);
      }
      *(uint4*)&f1b[(size_t)((z*KP + o)*KP + d0)] = u.v;
    } else if (t < TREST){
      int i = t - TE - TF1;
      int lane = i & 63; int g = i >> 6;   // g = kc*19 + pt
      int pt = g % 19, kc = g / 19;
      int p  = pt*16 + (lane & 15);
      int k0 = kc*32 + (lane >> 4)*8;
      union { unsigned short s[8]; uint4 v; } u;
      #pragma unroll
      for (int e = 0; e < 8; ++e){
        int k = k0 + e;
        float v = (p < DD && k < DD) ? fc3w[p*DD + k] : 0.f;
        u.s[e] = f2bf(v);
      }
      *(uint4*)&f3b[(size_t)i * 8] = u.v;
    }
  } else {
    // ---- spatial: box @ fc2 half; z=0 plain, z=1 frag-packed ----
    int sid = bid - XBLK - RBLK;
    int z = sid / 480;
    int tt = (sid - z*480) * 256 + tid;      // 0..122879
    float wa = wloc[0], wbv = wloc[1];
    float mm = fmaxf(wa, wbv);
    float ea = expf(wa - mm), eb = expf(wbv - mm);
    float w1 = eb / (ea + eb);
    int r = tt / KP, o = tt - r*KP;
    const float* bx = z ? box2 : box1;
    int joff = z ? 5 : 0;
    float v = 0.f;
    if (o < DD){
      const float* b = bx + r * 5;
      const float* wr = fc2w + o * 10 + joff;
      v = b[0]*wr[0] + b[1]*wr[1] + b[2]*wr[2] + b[3]*wr[3] + b[4]*wr[4];
      if (!z) v += fc2b[o];
      v *= w1;
    }
    if (z == 0) ws[OFF_CD + tt] = v;
    else {
      float* DPp = ws + OFF_CD + 384*KP;
      int mt = r >> 4, lm = r & 15, kcs = o >> 5, q_o = (o >> 3) & 3, e = o & 7;
      DPp[(mt*10 + kcs)*512 + (q_o*16 + lm)*8 + e] = v;
    }
  }
}

// ---------------------------------------------------------------------------
// gated GEMM: 4-way K-split, unchanged (proven).
// ---------------------------------------------------------------------------
__global__ __launch_bounds__(256) void k_gg(float* ws){
  __shared__ __align__(16) float red[4][64][4];   // 4 KB
  int z = blockIdx.y;
  const unsigned short* XP = (const unsigned short*)(ws + OFF_XBF) + (size_t)z*24*61*512;
  const unsigned short* EP = (const unsigned short*)(ws + OFF_EBT);
  unsigned short* out      = (unsigned short*)(ws + OFF_F1B) + z*384*KP;
  int t = threadIdx.x, lane = t & 63, wave = t >> 6;
  int id = blockIdx.x;                     // 0..479 tile id
  int mt = id / 20, ct = id - mt*20;
  const unsigned short* ap = XP + (size_t)mt*61*512 + lane*8;
  const unsigned short* bp = EP + (size_t)ct*61*512 + lane*8;
  int kc0 = wave*16;
  int kcn = (wave == 3) ? 13 : 16;
  floatx4 acc = (floatx4){0.f,0.f,0.f,0.f};
  for (int i = 0; i < kcn; ++i){
    int kc = kc0 + i;
    short8 a = *(const short8*)(ap + (size_t)kc*512);
    short8 b = *(const short8*)(bp + (size_t)kc*512);
    acc = __builtin_amdgcn_mfma_f32_16x16x32_bf16(a, b, acc, 0, 0, 0);
  }
  *(floatx4*)&red[wave][lane][0] = acc;
  __syncthreads();
  int r = t >> 6, lane2 = t & 63;
  float v = red[0][lane2][r] + red[1][lane2][r] + red[2][lane2][r] + red[3][lane2][r];
  int col = lane2 & 15, quad = lane2 >> 4;
  int m = mt*16 + quad*4 + r;
  int c = ct*16 + col;
  out[m*KP + c] = (c < DD) ? f2bf(v) : (unsigned short)0;
}

// ---------------------------------------------------------------------------
// semantic only: AB = w0*(F @ fc1^T (+b1)) — unchanged.
// ---------------------------------------------------------------------------
__global__ __launch_bounds__(256) void k_sem(const float* fc1b, const float* wloc, float* ws){
  int z = blockIdx.y;
  float wa = wloc[0], wbv = wloc[1];
  float mm = fmaxf(wa, wbv);
  float ea = expf(wa - mm), eb = expf(wbv - mm);
  float w0 = ea / (ea + eb);
  int t = threadIdx.x;
  const unsigned short* F = (const unsigned short*)(ws + OFF_F1B) + z*384*KP;
  const unsigned short* W = (const unsigned short*)(ws + OFF_FC1B) + z*KP*KP;
  int lane = t & 63;
  int id = blockIdx.x * 4 + (t >> 6);    // 0..479
  int rt = id / 20, ot = id - rt*20;
  int col = lane & 15, quad = lane >> 4;
  const unsigned short* ap = F + (rt*16 + col)*KP + quad*8;
  const unsigned short* bp = W + (ot*16 + col)*KP + quad*8;
  floatx4 acc = (floatx4){0.f,0.f,0.f,0.f};
  #pragma unroll
  for (int kc = 0; kc < 10; ++kc){
    short8 a = *(const short8*)(ap + kc*32);
    short8 b = *(const short8*)(bp + kc*32);
    acc = __builtin_amdgcn_mfma_f32_16x16x32_bf16(a, b, acc, 0, 0, 0);
  }
  int o = ot*16 + col;
  if (z == 0){
    float bias = (o < DD) ? fc1b[o] : 0.f;
    float* outp = ws + OFF_AB;
    #pragma unroll
    for (int r = 0; r < 4; ++r){
      int rr = rt*16 + quad*4 + r;
      outp[rr*KP + o] = (o < DD) ? w0 * (acc[r] + bias) : 0.f;
    }
  } else {
    float* BP = ws + OFF_AB + 384*KP;
    int kcs = o >> 5, q_o = (o >> 3) & 3, e = o & 7;
    #pragma unroll
    for (int r = 0; r < 4; ++r){
      int lm = quad*4 + r;
      BP[(rt*10 + kcs)*512 + (q_o*16 + lm)*8 + e] = (o < DD) ? w0 * acc[r] : 0.f;
    }
  }
}

// ---------------------------------------------------------------------------
// main v10: VALU diet + coalesced epilogue.
//  - native bf16 casts (pairable into v_cvt_pk_bf16_f32 by the compiler)
//  - pg-uniform MFMA loop: 9 unguarded + 1 conditional (drops per-pt compare)
//  - epilogue: acc+bias -> LDS (reusing wbuf: exactly 32x304 f32 = 38912 B),
//    then 2400 linear float4 stores — block output is one contiguous 38.4 KB
//    region (was 40 scattered dwords/thread, quarter-wave coalesced)
//  - keep: counted barrier, 2-deep prefetch, 256-thr blocks, bounds (256,3)
// ---------------------------------------------------------------------------
__global__ __launch_bounds__(256, 3) void k_main(const float* fc3b, float* out, const float* ws){
  __shared__ __align__(16) unsigned short wbuf[2][19*512];   // 2 x 19456 B
  const unsigned short* fc3p = (const unsigned short*)(ws + OFF_FC3B);
  int t = threadIdx.x;
  int lane = t & 63, wave = t >> 6;          // 0..3
  int col = lane & 15, quad = lane >> 4;
  int mtw = wave >> 1, pg = wave & 1;        // mt-sub, pt-group
  int n = blockIdx.y;
  int mt = blockIdx.x * 2 + mtw;             // 0..23
  const float* Ah = ws + OFF_AB + n * KP;
  const float* Ch = ws + OFF_CD + n * KP;
  const float* BP  = ws + OFF_AB + 384*KP + (size_t)mt*10*512 + lane*8;
  const float* DPp = ws + OFF_CD + 384*KP + (size_t)mt*10*512 + lane*8;

  floatx4 acc[10];
  #pragma unroll
  for (int i = 0; i < 10; ++i) acc[i] = (floatx4){0.f,0.f,0.f,0.f};

  // stage kc=0 weights (1216 uint4, 256 threads -> 5 chunks)
  {
    const uint4* src = (const uint4*)fc3p;
    uint4* dst = (uint4*)&wbuf[0][0];
    dst[t] = src[t]; dst[t + 256] = src[t + 256];
    dst[t + 512] = src[t + 512]; dst[t + 768] = src[t + 768];
    if (t < 192) dst[t + 1024] = src[t + 1024];
  }
  // preload kc=0 build operands
  float4 na0 = *(const float4*)(Ah + quad*8);
  float4 na1 = *(const float4*)(Ah + quad*8 + 4);
  float4 nc0 = *(const float4*)(Ch + quad*8);
  float4 nc1 = *(const float4*)(Ch + quad*8 + 4);
  float4 nb0 = *(const float4*)(BP);
  float4 nb1 = *(const float4*)(BP + 4);
  float4 nd0 = *(const float4*)(DPp);
  float4 nd1 = *(const float4*)(DPp + 4);
  __syncthreads();   // initial full drain (once)

  for (int kc = 0; kc < 10; ++kc){
    bool pre = (kc < 9);
    // weight prefetch for kc+1 (issued first; regs retire at ds_write)
    uint4 s0, s1, s2, s3, s4;
    if (pre){
      const uint4* src = (const uint4*)(fc3p + (size_t)(kc+1) * (19*512));
      s0 = src[t]; s1 = src[t + 256]; s2 = src[t + 512]; s3 = src[t + 768];
      if (t < 192) s4 = src[t + 1024];
    }
    float4 a0=na0, a1=na1, b0=nb0, b1=nb1, c0=nc0, c1=nc1, d0=nd0, d1=nd1;
    // issue next-kc build loads (stay in flight across the barrier)
    if (pre){
      int kb = (kc+1)*32 + quad*8;
      na0 = *(const float4*)(Ah + kb);   na1 = *(const float4*)(Ah + kb + 4);
      nc0 = *(const float4*)(Ch + kb);   nc1 = *(const float4*)(Ch + kb + 4);
      nb0 = *(const float4*)(BP + (kc+1)*512);  nb1 = *(const float4*)(BP + (kc+1)*512 + 4);
      nd0 = *(const float4*)(DPp + (kc+1)*512); nd1 = *(const float4*)(DPp + (kc+1)*512 + 4);
    }
    // build A-frag: mixed = relu(a+b)+relu(c+d); native RNE casts
    union { unsigned short s[8]; short8 v8; } u;
    u.s[0] = c2bf(fmaxf(a0.x + b0.x, 0.f) + fmaxf(c0.x + d0.x, 0.f));
    u.s[1] = c2bf(fmaxf(a0.y + b0.y, 0.f) + fmaxf(c0.y + d0.y, 0.f));
    u.s[2] = c2bf(fmaxf(a0.z + b0.z, 0.f) + fmaxf(c0.z + d0.z, 0.f));
    u.s[3] = c2bf(fmaxf(a0.w + b0.w, 0.f) + fmaxf(c0.w + d0.w, 0.f));
    u.s[4] = c2bf(fmaxf(a1.x + b1.x, 0.f) + fmaxf(c1.x + d1.x, 0.f));
    u.s[5] = c2bf(fmaxf(a1.y + b1.y, 0.f) + fmaxf(c1.y + d1.y, 0.f));
    u.s[6] = c2bf(fmaxf(a1.z + b1.z, 0.f) + fmaxf(c1.z + d1.z, 0.f));
    u.s[7] = c2bf(fmaxf(a1.w + b1.w, 0.f) + fmaxf(c1.w + d1.w, 0.f));
    short8 af = u.v8;
    const unsigned short* wpg = wbuf[kc & 1] + pg*10*512 + lane*8;
    #pragma unroll
    for (int i = 0; i < 9; ++i){
      short8 bf = *(const short8*)(wpg + i*512);
      acc[i] = __builtin_amdgcn_mfma_f32_16x16x32_bf16(af, bf, acc[i], 0, 0, 0);
    }
    if (pg == 0){
      short8 bf = *(const short8*)(wpg + 9*512);
      acc[9] = __builtin_amdgcn_mfma_f32_16x16x32_bf16(af, bf, acc[9], 0, 0, 0);
    }
    // write next weight slice, then barrier WITHOUT vmcnt drain
    if (pre){
      uint4* dst = (uint4*)&wbuf[(kc + 1) & 1][0];
      dst[t] = s0; dst[t + 256] = s1; dst[t + 512] = s2; dst[t + 768] = s3;
      if (t < 192) dst[t + 1024] = s4;
      asm volatile("s_waitcnt lgkmcnt(0)" ::: "memory");
      __builtin_amdgcn_s_barrier();
      __builtin_amdgcn_sched_barrier(0);   // rule #18: pin phase boundary
    }
  }

  // ---- epilogue: LDS bounce -> contiguous 38.4 KB block store ----
  __syncthreads();                          // all waves done reading wbuf
  float* sm = (float*)&wbuf[0][0];          // 32 x 304 f32 = 38912 B (exact)
  {
    int mloc0 = mtw*16 + quad*4;
    #pragma unroll
    for (int i = 0; i < 10; ++i){
      int pt = pg*10 + i;
      if (pt < 19){
        int p = pt*16 + col;
        float bias = (p < DD) ? fc3b[p] : 0.f;
        #pragma unroll
        for (int r = 0; r < 4; ++r)
          sm[(mloc0 + r)*304 + p] = acc[i][r] + bias;
      }
    }
  }
  __syncthreads();
  {
    float* ob = out + ((size_t)n * NROW + (size_t)blockIdx.x * 32) * DD;
    for (int c = t; c < 2400; c += 256){    // 32 rows x 75 float4
      int m = c / 75, p4 = c - m*75;
      float4 v = *(const float4*)&sm[m*304 + p4*4];
      *(float4*)&ob[(size_t)c*4] = v;       // linear: base + c*16B
    }
  }
}

extern "C" void kernel_launch(void* const* d_in, const int* in_sizes, int n_in,
                              void* d_out, int out_size, void* d_ws, size_t ws_size,
                              hipStream_t stream) {
  const float* feature1 = (const float*)d_in[0];
  const float* box1     = (const float*)d_in[1];
  const float* feature2 = (const float*)d_in[2];
  const float* box2     = (const float*)d_in[3];
  const float* E        = (const float*)d_in[4];
  const float* gate1    = (const float*)d_in[5];
  const float* gate2    = (const float*)d_in[6];
  const float* wloc     = (const float*)d_in[7];
  const float* fc1w     = (const float*)d_in[8];
  const float* fc1b     = (const float*)d_in[9];
  const float* fc2w     = (const float*)d_in[10];
  const float* fc2b     = (const float*)d_in[11];
  const float* fc3w     = (const float*)d_in[12];
  const float* fc3b     = (const float*)d_in[13];
  float* out = (float*)d_out;
  float* ws  = (float*)d_ws;

  hipLaunchKernelGGL(k_cvt_all, dim3(GRID_CVT), dim3(256), 0, stream,
                     feature1, feature2, E, gate1, gate2, fc1w, fc3w,
                     box1, box2, fc2w, fc2b, wloc, ws);
  hipLaunchKernelGGL(k_gg, dim3(480, 2), dim3(256), 0, stream, ws);
  hipLaunchKernelGGL(k_sem, dim3(120, 2), dim3(256), 0, stream, fc1b, wloc, ws);
  hipLaunchKernelGGL(k_main, dim3(12, NROW), dim3(256), 0, stream, fc3b, out, ws);
}